// Round 11
// baseline (454.649 us; speedup 1.0000x reference)
//
#include <hip/hip_runtime.h>
#include <math.h>

#define N_NODES 64000
#define N_EDGES 3200000
#define F0 1000
#define F1 32
#define F2 16
#define NGRAPH 64
#define KC 128            // 16000 = 125 blocks x 128
#define NBIN 250          // 256 nodes per bin
#define BINCAP 17408      // level-1 slots per bin (mean ~15.9K incl. padding)
#define EPB 4096          // edges per binning block
#define SLOTS 38          // LDS staging slots per bin
#define CAP 112           // per-node bucket capacity (deg ~ Poisson(50))
#define SEG 8             // segments for k_degp
#define NGEMMB 500        // 64000 / 128
#define NBINB  782        // ceil(3.2M / 4096)

// ---------------- zero scratch counters ----------------
__global__ __launch_bounds__(256) void k_zero(int* __restrict__ gcur,
                                              float* __restrict__ out1) {
    int t = blockIdx.x * 256 + threadIdx.x;
    if (t < NBIN) gcur[t] = 0;
    if (t < NGRAPH * 64) out1[t] = 0.f;
}

// ---------------- fused: edge binning (latency-bound) || GEMM1 (HBM-bound) ----------------
struct BinS  { uint2 stage[NBIN * SLOTS]; int scnt[256]; int gbase[256]; };   // 78 KB
struct GemmS { float xs[2][32][132]; float ws[2][32][32]; };                  // 41 KB
union SmemU  { BinS b; GemmS g; };

__device__ __forceinline__ void bin_body(BinS& S, int bb,
                                         const int* __restrict__ ei,
                                         const float* __restrict__ ew,
                                         int* __restrict__ gcur,
                                         uint2* __restrict__ es1) {
    int t = threadIdx.x;
    if (t < 256) S.scnt[t] = 0;
    __syncthreads();
    int e0 = bb * EPB;
#pragma unroll
    for (int r = 0; r < EPB / 512; ++r) {
        int e = e0 + r * 512 + t;
        if (e < N_EDGES) {
            int row = ei[e], c = ei[N_EDGES + e];
            float w = ew[e];
            int b = c >> 8;
            unsigned w0 = (unsigned)row | ((unsigned)(c & 255) << 17);
            int pos = atomicAdd(&S.scnt[b], 1);
            if (pos < SLOTS) {
                S.stage[b * SLOTS + pos] = make_uint2(w0, __float_as_uint(w));
            } else {  // rare overflow: aligned run of 8, 1 real + 7 pads
                int gb = atomicAdd(&gcur[b], 8);
                uint2* dst = &es1[(size_t)b * BINCAP + gb];
                dst[0] = make_uint2(w0, __float_as_uint(w));
#pragma unroll
                for (int z = 1; z < 8; ++z) dst[z] = make_uint2(0u, 0u);
            }
        }
    }
    __syncthreads();
    // phase 1: all bin reservations in parallel
    if (t < NBIN) {
        int cn = S.scnt[t]; if (cn > SLOTS) cn = SLOTS;
        int rn = (cn + 7) & ~7;
        S.gbase[t] = atomicAdd(&gcur[t], rn);
    }
    __syncthreads();
    // phase 2: wave-cooperative coalesced burst writes (8 waves)
    int wv = t >> 6, lane = t & 63;
    for (int b = wv; b < NBIN; b += 8) {
        int cn = S.scnt[b]; if (cn > SLOTS) cn = SLOTS;
        int rn = (cn + 7) & ~7;
        int gb = S.gbase[b];
        if (lane < rn) {
            uint2 v = (lane < cn) ? S.stage[b * SLOTS + lane] : make_uint2(0u, 0u);
            es1[(size_t)b * BINCAP + gb + lane] = v;
        }
    }
}

__device__ __forceinline__ void gemm_body(GemmS& S, int gb,
                                          const float* __restrict__ x,
                                          const float* __restrict__ W,
                                          float* __restrict__ xl) {
    int t = threadIdx.x;
    int row0 = gb * 128;
    int tr = t >> 4;            // 0..31 -> rows tr*4..tr*4+3
    int tc = t & 15;            // 0..15 -> cols tc*2, tc*2+1
    int sr = t >> 2;            // 0..127 staging row
    int sk = (t & 3) * 8;       // 0,8,16,24 staging k-offset (8 wide)

    float acc[4][2];
#pragma unroll
    for (int i = 0; i < 4; ++i) { acc[i][0] = 0.f; acc[i][1] = 0.f; }

    auto stage = [&](int k0, int buf) {
        if (t < 256) {
            int idx = t * 4;
            int gidx = k0 * F1 + idx;
            float4 v = make_float4(0.f, 0.f, 0.f, 0.f);
            if (gidx + 3 < F0 * F1) v = *(const float4*)&W[gidx];
            *(float4*)&((float*)S.ws[buf])[idx] = v;
        }
        float4 v0 = make_float4(0.f, 0.f, 0.f, 0.f);
        float4 v1 = make_float4(0.f, 0.f, 0.f, 0.f);
        if (k0 + sk < F0) {   // F0 % 8 == 0 -> guard covers both quads
            const float* xr = &x[(size_t)(row0 + sr) * F0 + k0 + sk];
            v0 = *(const float4*)&xr[0];
            v1 = *(const float4*)&xr[4];
        }
        S.xs[buf][sk + 0][sr] = v0.x; S.xs[buf][sk + 1][sr] = v0.y;
        S.xs[buf][sk + 2][sr] = v0.z; S.xs[buf][sk + 3][sr] = v0.w;
        S.xs[buf][sk + 4][sr] = v1.x; S.xs[buf][sk + 5][sr] = v1.y;
        S.xs[buf][sk + 6][sr] = v1.z; S.xs[buf][sk + 7][sr] = v1.w;
    };
    auto compute = [&](int buf) {
#pragma unroll 8
        for (int kk = 0; kk < 32; ++kk) {
            float4 xa = *(const float4*)&S.xs[buf][kk][tr * 4];
            float2 wv = *(const float2*)&S.ws[buf][kk][tc * 2];
            acc[0][0] += xa.x * wv.x; acc[0][1] += xa.x * wv.y;
            acc[1][0] += xa.y * wv.x; acc[1][1] += xa.y * wv.y;
            acc[2][0] += xa.z * wv.x; acc[2][1] += xa.z * wv.y;
            acc[3][0] += xa.w * wv.x; acc[3][1] += xa.w * wv.y;
        }
    };

    stage(0, 0);
    int buf = 0;
    for (int c = 0; c < 31; ++c) {
        __syncthreads();
        stage((c + 1) * 32, buf ^ 1);   // loads for c+1 fly under compute of c
        compute(buf);
        buf ^= 1;
    }
    __syncthreads();
    compute(buf);

#pragma unroll
    for (int i = 0; i < 4; ++i) {
        int row = row0 + tr * 4 + i;
        *(float2*)&xl[(size_t)row * F1 + tc * 2] = make_float2(acc[i][0], acc[i][1]);
    }
}

__global__ __launch_bounds__(512) void k_binmm(const int* __restrict__ ei,
                                               const float* __restrict__ ew,
                                               int* __restrict__ gcur,
                                               uint2* __restrict__ es1,
                                               const float* __restrict__ x,
                                               const float* __restrict__ W,
                                               float* __restrict__ xl) {
    __shared__ SmemU S;
    int b = blockIdx.x;
    // interleave roles 1:1 for the first 1000 blocks -> resident mix on every CU
    if (b < 2 * NGEMMB) {
        if ((b & 1) == 0) gemm_body(S.g, b >> 1, x, W, xl);
        else              bin_body(S.b, b >> 1, ei, ew, gcur, es1);
    } else {
        bin_body(S.b, NGEMMB + (b - 2 * NGEMMB), ei, ew, gcur, es1);
    }
}

// ---------------- weighted degree, segmented partials (no global atomics) ----------------
__global__ __launch_bounds__(256) void k_degp(const int* __restrict__ gcur,
                                              const uint2* __restrict__ es1,
                                              float* __restrict__ deg_part) {
    __shared__ float dacc[256];
    int t = threadIdx.x;
    int bin = blockIdx.x >> 3, seg = blockIdx.x & (SEG - 1);
    dacc[t] = 0.f;
    __syncthreads();
    int cnt1 = gcur[bin];
    int chunk = (cnt1 + SEG - 1) / SEG;
    int lo = seg * chunk, hi = lo + chunk; if (hi > cnt1) hi = cnt1;
    const uint2* bp = &es1[(size_t)bin * BINCAP];
    for (int i = lo + t; i < hi; i += 256) {
        uint2 ed = bp[i];
        atomicAdd(&dacc[ed.x >> 17], __uint_as_float(ed.y));  // pads add 0
    }
    __syncthreads();
    deg_part[(size_t)blockIdx.x * 256 + t] = dacc[t];
}

__global__ __launch_bounds__(256) void k_dinv(const float* __restrict__ deg_part,
                                              float* __restrict__ dinv) {
    int n = blockIdx.x * 256 + threadIdx.x;   // bin = blockIdx.x
    float s = 0.f;
#pragma unroll
    for (int seg = 0; seg < SEG; ++seg)
        s += deg_part[((size_t)blockIdx.x * SEG + seg) * 256 + threadIdx.x];
    dinv[n] = rsqrtf(s + 1.0f);               // +1 = self-loop
}

// ---------------- level 2: scatter into per-node buckets with PRE-NORMALIZED weight ----------------
__global__ __launch_bounds__(1024) void k_sub(const int* __restrict__ gcur,
                                              const uint2* __restrict__ es1,
                                              const float* __restrict__ dinv,
                                              uint2* __restrict__ es2,
                                              int* __restrict__ cnta) {
    __shared__ int slot[256];
    __shared__ float dinvc[256];
    int t = threadIdx.x, bin = blockIdx.x;
    if (t < 256) { slot[t] = 0; dinvc[t] = dinv[bin * 256 + t]; }
    __syncthreads();
    int cnt1 = gcur[bin];
    const uint2* bp = &es1[(size_t)bin * BINCAP];
    for (int i = t; i < cnt1; i += 1024) {
        uint2 ed = bp[i];
        if (ed.y != 0u) {   // skip pads
            int c8 = ed.x >> 17;
            int row = ed.x & 0x1FFFF;
            float nv = dinv[row] * __uint_as_float(ed.y) * dinvc[c8];
            int p = atomicAdd(&slot[c8], 1);
            if (p < CAP)
                es2[((size_t)(bin * 256 + c8)) * CAP + p] =
                    make_uint2((unsigned)row, __float_as_uint(nv));
        }
    }
    __syncthreads();
    if (t < 256) {
        int c = slot[t]; if (c > CAP) c = CAP;
        cnta[bin * 256 + t] = c;
    }
}

// ---------------- gather layer1 + finish + GEMM2 fused ----------------
__global__ __launch_bounds__(256) void k_gather1(const int* __restrict__ cnta,
                                                 const uint2* __restrict__ es2,
                                                 const float* __restrict__ xl1,
                                                 const float* __restrict__ dinv,
                                                 const float* __restrict__ b1,
                                                 const float* __restrict__ W2,
                                                 float* __restrict__ xl2) {
    __shared__ float h1s[32][33];
    __shared__ float w2s[512];
    int t = threadIdx.x;
    if (t < 128) *(float4*)&w2s[t * 4] = *(const float4*)&W2[t * 4];
    int n = blockIdx.x * 32 + (t >> 3);
    int f4 = (t & 7) * 4;
    int cnt = cnta[n];
    float din = dinv[n];
    const uint2* bp = &es2[(size_t)n * CAP];
    float ax = 0.f, ay = 0.f, az = 0.f, aw = 0.f;
    float bx = 0.f, by = 0.f, bz = 0.f, bw = 0.f;
    int i = 0;
    uint4 cur = make_uint4(0u, 0u, 0u, 0u);
    if (cnt >= 2) cur = *(const uint4*)&bp[0];
    for (; i + 1 < cnt; i += 2) {
        uint4 nxt = make_uint4(0u, 0u, 0u, 0u);
        if (i + 3 < cnt) nxt = *(const uint4*)&bp[i + 2];
        float4 x0 = *(const float4*)&xl1[(size_t)cur.x * F1 + f4];
        float4 x1 = *(const float4*)&xl1[(size_t)cur.z * F1 + f4];
        float n0 = __uint_as_float(cur.y), n1 = __uint_as_float(cur.w);
        ax += n0 * x0.x; ay += n0 * x0.y; az += n0 * x0.z; aw += n0 * x0.w;
        bx += n1 * x1.x; by += n1 * x1.y; bz += n1 * x1.z; bw += n1 * x1.w;
        cur = nxt;
    }
    if (i < cnt) {
        uint2 ed = bp[i];
        float4 x0 = *(const float4*)&xl1[(size_t)ed.x * F1 + f4];
        float n0 = __uint_as_float(ed.y);
        ax += n0 * x0.x; ay += n0 * x0.y; az += n0 * x0.z; aw += n0 * x0.w;
    }
    float d2 = din * din;
    float4 sv = *(const float4*)&xl1[(size_t)n * F1 + f4];
    int nn = t >> 3;
    h1s[nn][f4 + 0] = fmaxf(ax + bx + d2 * sv.x + b1[f4 + 0], 0.f);
    h1s[nn][f4 + 1] = fmaxf(ay + by + d2 * sv.y + b1[f4 + 1], 0.f);
    h1s[nn][f4 + 2] = fmaxf(az + bz + d2 * sv.z + b1[f4 + 2], 0.f);
    h1s[nn][f4 + 3] = fmaxf(aw + bw + d2 * sv.w + b1[f4 + 3], 0.f);
    __syncthreads();
    int j0 = (t & 7) * 2;
    float a0 = 0.f, a1 = 0.f;
#pragma unroll 8
    for (int k = 0; k < 32; ++k) {
        float hv = h1s[nn][k];
        a0 += hv * w2s[k * 16 + j0];
        a1 += hv * w2s[k * 16 + j0 + 1];
    }
    *(float2*)&xl2[(size_t)(blockIdx.x * 32 + nn) * F2 + j0] = make_float2(a0, a1);
}

// ---------------- gather layer2 + finish -> h2 ----------------
__global__ __launch_bounds__(256) void k_gather2(const int* __restrict__ cnta,
                                                 const uint2* __restrict__ es2,
                                                 const float* __restrict__ xl2,
                                                 const float* __restrict__ dinv,
                                                 const float* __restrict__ b2,
                                                 float* __restrict__ h2) {
    int t = threadIdx.x;
    int n = blockIdx.x * 64 + (t >> 2);
    int f4 = (t & 3) * 4;
    int cnt = cnta[n];
    float din = dinv[n];
    const uint2* bp = &es2[(size_t)n * CAP];
    float ax = 0.f, ay = 0.f, az = 0.f, aw = 0.f;
    float bx = 0.f, by = 0.f, bz = 0.f, bw = 0.f;
    int i = 0;
    uint4 cur = make_uint4(0u, 0u, 0u, 0u);
    if (cnt >= 2) cur = *(const uint4*)&bp[0];
    for (; i + 1 < cnt; i += 2) {
        uint4 nxt = make_uint4(0u, 0u, 0u, 0u);
        if (i + 3 < cnt) nxt = *(const uint4*)&bp[i + 2];
        float4 x0 = *(const float4*)&xl2[(size_t)cur.x * F2 + f4];
        float4 x1 = *(const float4*)&xl2[(size_t)cur.z * F2 + f4];
        float n0 = __uint_as_float(cur.y), n1 = __uint_as_float(cur.w);
        ax += n0 * x0.x; ay += n0 * x0.y; az += n0 * x0.z; aw += n0 * x0.w;
        bx += n1 * x1.x; by += n1 * x1.y; bz += n1 * x1.z; bw += n1 * x1.w;
        cur = nxt;
    }
    if (i < cnt) {
        uint2 ed = bp[i];
        float4 x0 = *(const float4*)&xl2[(size_t)ed.x * F2 + f4];
        float n0 = __uint_as_float(ed.y);
        ax += n0 * x0.x; ay += n0 * x0.y; az += n0 * x0.z; aw += n0 * x0.w;
    }
    float d2 = din * din;
    float4 sv = *(const float4*)&xl2[(size_t)n * F2 + f4];
    float4 o;
    o.x = fmaxf(ax + bx + d2 * sv.x + b2[f4 + 0], 0.f);
    o.y = fmaxf(ay + by + d2 * sv.y + b2[f4 + 1], 0.f);
    o.z = fmaxf(az + bz + d2 * sv.z + b2[f4 + 2], 0.f);
    o.w = fmaxf(aw + bw + d2 * sv.w + b2[f4 + 3], 0.f);
    *(float4*)&h2[(size_t)n * F2 + f4] = o;
}

// ---------------- FC1 partial: KC=128, padded LDS ----------------
__global__ __launch_bounds__(256) void k_fc1(const float* __restrict__ h2,
                                             const float* __restrict__ wf1,
                                             float* __restrict__ out1) {
    __shared__ float wfs[KC * 64];     // 32 KB
    __shared__ float h2s[64][KC + 1];  // 33 KB, stride 129 kills bank conflicts
    int t = threadIdx.x;
    int k0 = blockIdx.x * KC;
    for (int idx = t * 4; idx < KC * 64; idx += 1024)
        *(float4*)&wfs[idx] = *(const float4*)&wf1[(size_t)k0 * 64 + idx];
    for (int idx = t; idx < 64 * (KC / 4); idx += 256) {
        int g = idx >> 5, j = idx & 31;   // KC/4 = 32 float4 per row
        *(float4*)&h2s[g][j * 4] = *(const float4*)&h2[(size_t)g * 16000 + k0 + j * 4];
    }
    __syncthreads();
    int g = t >> 2, jg = t & 3;
    float acc[16];
#pragma unroll
    for (int jj = 0; jj < 16; ++jj) acc[jj] = 0.f;
#pragma unroll 4
    for (int k = 0; k < KC; ++k) {
        float hv = h2s[g][k];
#pragma unroll
        for (int j4 = 0; j4 < 4; ++j4) {
            float4 wv = *(const float4*)&wfs[k * 64 + jg * 16 + j4 * 4];
            acc[j4 * 4 + 0] += hv * wv.x; acc[j4 * 4 + 1] += hv * wv.y;
            acc[j4 * 4 + 2] += hv * wv.z; acc[j4 * 4 + 3] += hv * wv.w;
        }
    }
#pragma unroll
    for (int jj = 0; jj < 16; ++jj)
        unsafeAtomicAdd(&out1[g * 64 + jg * 16 + jj], acc[jj]);
}

// ---------------- FC2 + sigmoid ----------------
__global__ void k_fc2(const float* __restrict__ out1, const float* __restrict__ bf1,
                      const float* __restrict__ wf2, const float* __restrict__ bf2,
                      float* __restrict__ out) {
    int g = threadIdx.x;
    if (g < NGRAPH) {
        float acc = bf2[0];
        for (int j = 0; j < 64; ++j)
            acc += fmaxf(out1[g * 64 + j] + bf1[j], 0.f) * wf2[j];
        out[g] = 1.f / (1.f + expf(-acc));
    }
}

extern "C" void kernel_launch(void* const* d_in, const int* in_sizes, int n_in,
                              void* d_out, int out_size, void* d_ws, size_t ws_size,
                              hipStream_t stream) {
    const float* x   = (const float*)d_in[0];
    const int*   ei  = (const int*)d_in[1];
    const float* ew  = (const float*)d_in[2];
    const float* W1  = (const float*)d_in[3];
    const float* b1  = (const float*)d_in[4];
    const float* W2  = (const float*)d_in[5];
    const float* b2  = (const float*)d_in[6];
    const float* Wf1 = (const float*)d_in[7];
    const float* bf1 = (const float*)d_in[8];
    const float* Wf2 = (const float*)d_in[9];
    const float* bf2 = (const float*)d_in[10];
    float* out = (float*)d_out;

    char* ws = (char*)d_ws;
    size_t off = 0;
    auto alloc = [&](size_t bytes) {
        void* p = ws + off;
        off += (bytes + 255) & ~(size_t)255;
        return p;
    };
    uint2* es2 = (uint2*)alloc((size_t)N_NODES * CAP * 8);     // 57.3 MB
    // es1 must NOT alias xl1 now (binning and gemm1 run concurrently)
    uint2* es1 = (uint2*)alloc((size_t)NBIN * BINCAP * 8);     // 34.8 MB
    float* xl1 = (float*)alloc((size_t)N_NODES * F1 * 4);      // 8.2 MB
    float* xl2 = (float*)alloc((size_t)N_NODES * F2 * 4);      // 4.1 MB
    float* h2  = (float*)alloc((size_t)N_NODES * F2 * 4);      // 4.1 MB
    float* deg_part = (float*)alloc((size_t)NBIN * SEG * 256 * 4);  // 2.0 MB
    float* dinv = (float*)alloc((size_t)N_NODES * 4);
    float* out1 = (float*)alloc(64 * 64 * 4);
    int*   cnta = (int*)alloc((size_t)N_NODES * 4);
    int*   gcur = (int*)alloc((size_t)NBIN * 4);

    k_zero<<<17, 256, 0, stream>>>(gcur, out1);
    k_binmm<<<2 * NGEMMB + (NBINB - NGEMMB), 512, 0, stream>>>(ei, ew, gcur, es1,
                                                               x, W1, xl1);
    k_degp<<<NBIN * SEG, 256, 0, stream>>>(gcur, es1, deg_part);
    k_dinv<<<NBIN, 256, 0, stream>>>(deg_part, dinv);
    k_sub<<<NBIN, 1024, 0, stream>>>(gcur, es1, dinv, es2, cnta);
    k_gather1<<<N_NODES / 32, 256, 0, stream>>>(cnta, es2, xl1, dinv, b1, W2, xl2);
    k_gather2<<<N_NODES / 64, 256, 0, stream>>>(cnta, es2, xl2, dinv, b2, h2);
    k_fc1<<<16000 / KC, 256, 0, stream>>>(h2, Wf1, out1);
    k_fc2<<<1, 64, 0, stream>>>(out1, bf1, Wf2, bf2, out);
}

// Round 12
// 354.056 us; speedup vs baseline: 1.2841x; 1.2841x over previous
//
#include <hip/hip_runtime.h>
#include <math.h>

#define N_NODES 64000
#define N_EDGES 3200000
#define F0 1000
#define F1 32
#define F2 16
#define NGRAPH 64
#define KC 128            // 16000 = 125 blocks x 128
#define NBIN 250          // 256 nodes per bin
#define BINCAP 17408      // level-1 slots per bin (mean ~15.9K incl. padding)
#define EPB 4096          // edges per binning block
#define SLOTS 38          // LDS staging slots per bin
#define CAP 112           // per-node bucket capacity (deg ~ Poisson(50))
#define SEG 8             // segments for k_degp
#define NFC1B 125         // 16000 / KC

// ---------------- zero scratch counters ----------------
__global__ __launch_bounds__(256) void k_zero(int* __restrict__ gcur,
                                              float* __restrict__ out1,
                                              int* __restrict__ ticket) {
    int t = blockIdx.x * 256 + threadIdx.x;
    if (t < NBIN) gcur[t] = 0;
    if (t < NGRAPH * 64) out1[t] = 0.f;
    if (t == 0) *ticket = 0;
}

// ---------------- level 1: group edges by col>>8 ----------------
// es1 entry: word0 = row | (col&255)<<17 ; word1 = fp32 weight. Pads are (0,0) -> w==0.
// 512 threads; flush = parallel atomics -> barrier -> wave burst (uint4 pairs).
__global__ __launch_bounds__(512) void k_bin(const int* __restrict__ ei,
                                             const float* __restrict__ ew,
                                             int* __restrict__ gcur,
                                             uint2* __restrict__ es1) {
    __shared__ uint2 stage[NBIN * SLOTS];   // 76 KB
    __shared__ int scnt[256];
    __shared__ int gbase[256];
    int t = threadIdx.x;
    if (t < 256) scnt[t] = 0;
    __syncthreads();
    int e0 = blockIdx.x * EPB;
#pragma unroll
    for (int r = 0; r < EPB / 512; ++r) {
        int e = e0 + r * 512 + t;
        if (e < N_EDGES) {
            int row = ei[e], c = ei[N_EDGES + e];
            float w = ew[e];
            int b = c >> 8;
            unsigned w0 = (unsigned)row | ((unsigned)(c & 255) << 17);
            int pos = atomicAdd(&scnt[b], 1);
            if (pos < SLOTS) {
                stage[b * SLOTS + pos] = make_uint2(w0, __float_as_uint(w));
            } else {  // rare overflow: aligned run of 8, 1 real + 7 pads
                int gb = atomicAdd(&gcur[b], 8);
                uint2* dst = &es1[(size_t)b * BINCAP + gb];
                dst[0] = make_uint2(w0, __float_as_uint(w));
#pragma unroll
                for (int z = 1; z < 8; ++z) dst[z] = make_uint2(0u, 0u);
            }
        }
    }
    __syncthreads();
    // phase 1: all bin reservations in parallel (latency overlaps)
    if (t < NBIN) {
        int cn = scnt[t]; if (cn > SLOTS) cn = SLOTS;
        int rn = (cn + 7) & ~7;              // line-aligned run
        gbase[t] = atomicAdd(&gcur[t], rn);
    }
    __syncthreads();                          // gbase visible to all
    // phase 2: wave-cooperative burst writes, 2 entries (16B) per lane
    int wv = t >> 6, lane = t & 63;
    for (int b = wv; b < NBIN; b += 8) {
        int cn = scnt[b]; if (cn > SLOTS) cn = SLOTS;
        int rn = (cn + 7) & ~7;
        int gb = gbase[b];
        int k = lane * 2;
        if (k < rn) {
            uint2 v0 = (k     < cn) ? stage[b * SLOTS + k    ] : make_uint2(0u, 0u);
            uint2 v1 = (k + 1 < cn) ? stage[b * SLOTS + k + 1] : make_uint2(0u, 0u);
            uint4 v = make_uint4(v0.x, v0.y, v1.x, v1.y);
            *(uint4*)&es1[(size_t)b * BINCAP + gb + k] = v;   // gb,k even -> 16B aligned
        }
    }
}

// ---------------- weighted degree, segmented partials (no global atomics) ----------------
__global__ __launch_bounds__(256) void k_degp(const int* __restrict__ gcur,
                                              const uint2* __restrict__ es1,
                                              float* __restrict__ deg_part) {
    __shared__ float dacc[256];
    int t = threadIdx.x;
    int bin = blockIdx.x >> 3, seg = blockIdx.x & (SEG - 1);
    dacc[t] = 0.f;
    __syncthreads();
    int cnt1 = gcur[bin];
    int chunk = (cnt1 + SEG - 1) / SEG;
    int lo = seg * chunk, hi = lo + chunk; if (hi > cnt1) hi = cnt1;
    const uint2* bp = &es1[(size_t)bin * BINCAP];
    for (int i = lo + t; i < hi; i += 256) {
        uint2 ed = bp[i];
        atomicAdd(&dacc[ed.x >> 17], __uint_as_float(ed.y));  // pads add 0
    }
    __syncthreads();
    deg_part[(size_t)blockIdx.x * 256 + t] = dacc[t];
}

__global__ __launch_bounds__(256) void k_dinv(const float* __restrict__ deg_part,
                                              float* __restrict__ dinv) {
    int n = blockIdx.x * 256 + threadIdx.x;   // bin = blockIdx.x
    float s = 0.f;
#pragma unroll
    for (int seg = 0; seg < SEG; ++seg)
        s += deg_part[((size_t)blockIdx.x * SEG + seg) * 256 + threadIdx.x];
    dinv[n] = rsqrtf(s + 1.0f);               // +1 = self-loop
}

// ---------------- level 2: scatter into per-node buckets with PRE-NORMALIZED weight ----------------
__global__ __launch_bounds__(1024) void k_sub(const int* __restrict__ gcur,
                                              const uint2* __restrict__ es1,
                                              const float* __restrict__ dinv,
                                              uint2* __restrict__ es2,
                                              int* __restrict__ cnta) {
    __shared__ int slot[256];
    __shared__ float dinvc[256];
    int t = threadIdx.x, bin = blockIdx.x;
    if (t < 256) { slot[t] = 0; dinvc[t] = dinv[bin * 256 + t]; }
    __syncthreads();
    int cnt1 = gcur[bin];
    const uint2* bp = &es1[(size_t)bin * BINCAP];
    for (int i = t; i < cnt1; i += 1024) {
        uint2 ed = bp[i];
        if (ed.y != 0u) {   // skip pads
            int c8 = ed.x >> 17;
            int row = ed.x & 0x1FFFF;
            float nv = dinv[row] * __uint_as_float(ed.y) * dinvc[c8];
            int p = atomicAdd(&slot[c8], 1);
            if (p < CAP)
                es2[((size_t)(bin * 256 + c8)) * CAP + p] =
                    make_uint2((unsigned)row, __float_as_uint(nv));
        }
    }
    __syncthreads();
    if (t < 256) {
        int c = slot[t]; if (c > CAP) c = CAP;
        cnta[bin * 256 + t] = c;
    }
}

// ---------------- GEMM1: xl1[N,32] = x[N,1000] @ W1[1000,32], double-buffered ----------------
__global__ __launch_bounds__(256) void k_gemm1(const float* __restrict__ x,
                                               const float* __restrict__ W,
                                               float* __restrict__ xl) {
    __shared__ float xs[2][32][132];
    __shared__ float ws[2][32][32];
    int t = threadIdx.x;
    int row0 = blockIdx.x * 128;
    int rsub = t >> 3;
    int kk4  = (t & 7) * 4;
    int tr = t >> 3;
    int tc = t & 7;

    float acc[4][4];
#pragma unroll
    for (int i = 0; i < 4; ++i)
#pragma unroll
        for (int j = 0; j < 4; ++j) acc[i][j] = 0.f;

    auto stage = [&](int k0, int buf) {
        int idx = t * 4;
        int gidx = k0 * F1 + idx;
        float4 v = make_float4(0.f, 0.f, 0.f, 0.f);
        if (gidx + 3 < F0 * F1) v = *(const float4*)&W[gidx];
        *(float4*)&((float*)ws[buf])[idx] = v;
#pragma unroll
        for (int p = 0; p < 4; ++p) {
            int r = p * 32 + rsub;
            float4 xv = make_float4(0.f, 0.f, 0.f, 0.f);
            if (k0 + kk4 < F0)
                xv = *(const float4*)&x[(size_t)(row0 + r) * F0 + k0 + kk4];
            xs[buf][kk4 + 0][r] = xv.x; xs[buf][kk4 + 1][r] = xv.y;
            xs[buf][kk4 + 2][r] = xv.z; xs[buf][kk4 + 3][r] = xv.w;
        }
    };
    auto compute = [&](int buf) {
#pragma unroll 8
        for (int kk = 0; kk < 32; ++kk) {
            float4 xa = *(const float4*)&xs[buf][kk][tr * 4];
            float4 wv = *(const float4*)&ws[buf][kk][tc * 4];
            float xv[4] = {xa.x, xa.y, xa.z, xa.w};
            float wl[4] = {wv.x, wv.y, wv.z, wv.w};
#pragma unroll
            for (int i = 0; i < 4; ++i)
#pragma unroll
                for (int j = 0; j < 4; ++j) acc[i][j] += xv[i] * wl[j];
        }
    };

    stage(0, 0);
    int buf = 0;
    for (int c = 0; c < 31; ++c) {
        __syncthreads();
        stage((c + 1) * 32, buf ^ 1);   // loads for c+1 fly under compute of c
        compute(buf);
        buf ^= 1;
    }
    __syncthreads();
    compute(buf);

#pragma unroll
    for (int i = 0; i < 4; ++i) {
        int row = row0 + tr * 4 + i;
        float4 v = make_float4(acc[i][0], acc[i][1], acc[i][2], acc[i][3]);
        *(float4*)&xl[(size_t)row * F1 + tc * 4] = v;
    }
}

// ---------------- gather layer1 + finish + GEMM2 fused ----------------
__global__ __launch_bounds__(256) void k_gather1(const int* __restrict__ cnta,
                                                 const uint2* __restrict__ es2,
                                                 const float* __restrict__ xl1,
                                                 const float* __restrict__ dinv,
                                                 const float* __restrict__ b1,
                                                 const float* __restrict__ W2,
                                                 float* __restrict__ xl2) {
    __shared__ float h1s[32][33];
    __shared__ float w2s[512];
    int t = threadIdx.x;
    if (t < 128) *(float4*)&w2s[t * 4] = *(const float4*)&W2[t * 4];
    int n = blockIdx.x * 32 + (t >> 3);
    int f4 = (t & 7) * 4;
    int cnt = cnta[n];
    float din = dinv[n];
    const uint2* bp = &es2[(size_t)n * CAP];
    float ax = 0.f, ay = 0.f, az = 0.f, aw = 0.f;
    float bx = 0.f, by = 0.f, bz = 0.f, bw = 0.f;
    int i = 0;
    uint4 cur = make_uint4(0u, 0u, 0u, 0u);
    if (cnt >= 2) cur = *(const uint4*)&bp[0];
    for (; i + 1 < cnt; i += 2) {
        uint4 nxt = make_uint4(0u, 0u, 0u, 0u);
        if (i + 3 < cnt) nxt = *(const uint4*)&bp[i + 2];
        float4 x0 = *(const float4*)&xl1[(size_t)cur.x * F1 + f4];
        float4 x1 = *(const float4*)&xl1[(size_t)cur.z * F1 + f4];
        float n0 = __uint_as_float(cur.y), n1 = __uint_as_float(cur.w);
        ax += n0 * x0.x; ay += n0 * x0.y; az += n0 * x0.z; aw += n0 * x0.w;
        bx += n1 * x1.x; by += n1 * x1.y; bz += n1 * x1.z; bw += n1 * x1.w;
        cur = nxt;
    }
    if (i < cnt) {
        uint2 ed = bp[i];
        float4 x0 = *(const float4*)&xl1[(size_t)ed.x * F1 + f4];
        float n0 = __uint_as_float(ed.y);
        ax += n0 * x0.x; ay += n0 * x0.y; az += n0 * x0.z; aw += n0 * x0.w;
    }
    float d2 = din * din;
    float4 sv = *(const float4*)&xl1[(size_t)n * F1 + f4];
    int nn = t >> 3;
    h1s[nn][f4 + 0] = fmaxf(ax + bx + d2 * sv.x + b1[f4 + 0], 0.f);
    h1s[nn][f4 + 1] = fmaxf(ay + by + d2 * sv.y + b1[f4 + 1], 0.f);
    h1s[nn][f4 + 2] = fmaxf(az + bz + d2 * sv.z + b1[f4 + 2], 0.f);
    h1s[nn][f4 + 3] = fmaxf(aw + bw + d2 * sv.w + b1[f4 + 3], 0.f);
    __syncthreads();
    int j0 = (t & 7) * 2;
    float a0 = 0.f, a1 = 0.f;
#pragma unroll 8
    for (int k = 0; k < 32; ++k) {
        float hv = h1s[nn][k];
        a0 += hv * w2s[k * 16 + j0];
        a1 += hv * w2s[k * 16 + j0 + 1];
    }
    *(float2*)&xl2[(size_t)(blockIdx.x * 32 + nn) * F2 + j0] = make_float2(a0, a1);
}

// ---------------- gather layer2 + finish -> h2 ----------------
__global__ __launch_bounds__(256) void k_gather2(const int* __restrict__ cnta,
                                                 const uint2* __restrict__ es2,
                                                 const float* __restrict__ xl2,
                                                 const float* __restrict__ dinv,
                                                 const float* __restrict__ b2,
                                                 float* __restrict__ h2) {
    int t = threadIdx.x;
    int n = blockIdx.x * 64 + (t >> 2);
    int f4 = (t & 3) * 4;
    int cnt = cnta[n];
    float din = dinv[n];
    const uint2* bp = &es2[(size_t)n * CAP];
    float ax = 0.f, ay = 0.f, az = 0.f, aw = 0.f;
    float bx = 0.f, by = 0.f, bz = 0.f, bw = 0.f;
    int i = 0;
    uint4 cur = make_uint4(0u, 0u, 0u, 0u);
    if (cnt >= 2) cur = *(const uint4*)&bp[0];
    for (; i + 1 < cnt; i += 2) {
        uint4 nxt = make_uint4(0u, 0u, 0u, 0u);
        if (i + 3 < cnt) nxt = *(const uint4*)&bp[i + 2];
        float4 x0 = *(const float4*)&xl2[(size_t)cur.x * F2 + f4];
        float4 x1 = *(const float4*)&xl2[(size_t)cur.z * F2 + f4];
        float n0 = __uint_as_float(cur.y), n1 = __uint_as_float(cur.w);
        ax += n0 * x0.x; ay += n0 * x0.y; az += n0 * x0.z; aw += n0 * x0.w;
        bx += n1 * x1.x; by += n1 * x1.y; bz += n1 * x1.z; bw += n1 * x1.w;
        cur = nxt;
    }
    if (i < cnt) {
        uint2 ed = bp[i];
        float4 x0 = *(const float4*)&xl2[(size_t)ed.x * F2 + f4];
        float n0 = __uint_as_float(ed.y);
        ax += n0 * x0.x; ay += n0 * x0.y; az += n0 * x0.z; aw += n0 * x0.w;
    }
    float d2 = din * din;
    float4 sv = *(const float4*)&xl2[(size_t)n * F2 + f4];
    float4 o;
    o.x = fmaxf(ax + bx + d2 * sv.x + b2[f4 + 0], 0.f);
    o.y = fmaxf(ay + by + d2 * sv.y + b2[f4 + 1], 0.f);
    o.z = fmaxf(az + bz + d2 * sv.z + b2[f4 + 2], 0.f);
    o.w = fmaxf(aw + bw + d2 * sv.w + b2[f4 + 3], 0.f);
    *(float4*)&h2[(size_t)n * F2 + f4] = o;
}

// ---------------- FC1 partial + ticket-fused FC2 ----------------
__global__ __launch_bounds__(256) void k_fc1(const float* __restrict__ h2,
                                             const float* __restrict__ wf1,
                                             float* __restrict__ out1,
                                             int* __restrict__ ticket,
                                             const float* __restrict__ bf1,
                                             const float* __restrict__ wf2,
                                             const float* __restrict__ bf2,
                                             float* __restrict__ out) {
    __shared__ float wfs[KC * 64];     // 32 KB
    __shared__ float h2s[64][KC + 1];  // 33 KB, stride 129 kills bank conflicts
    __shared__ int last;
    int t = threadIdx.x;
    int k0 = blockIdx.x * KC;
    for (int idx = t * 4; idx < KC * 64; idx += 1024)
        *(float4*)&wfs[idx] = *(const float4*)&wf1[(size_t)k0 * 64 + idx];
    for (int idx = t; idx < 64 * (KC / 4); idx += 256) {
        int g = idx >> 5, j = idx & 31;   // KC/4 = 32 float4 per row
        *(float4*)&h2s[g][j * 4] = *(const float4*)&h2[(size_t)g * 16000 + k0 + j * 4];
    }
    __syncthreads();
    int g = t >> 2, jg = t & 3;
    float acc[16];
#pragma unroll
    for (int jj = 0; jj < 16; ++jj) acc[jj] = 0.f;
#pragma unroll 4
    for (int k = 0; k < KC; ++k) {
        float hv = h2s[g][k];
#pragma unroll
        for (int j4 = 0; j4 < 4; ++j4) {
            float4 wv = *(const float4*)&wfs[k * 64 + jg * 16 + j4 * 4];
            acc[j4 * 4 + 0] += hv * wv.x; acc[j4 * 4 + 1] += hv * wv.y;
            acc[j4 * 4 + 2] += hv * wv.z; acc[j4 * 4 + 3] += hv * wv.w;
        }
    }
#pragma unroll
    for (int jj = 0; jj < 16; ++jj)
        unsafeAtomicAdd(&out1[g * 64 + jg * 16 + jj], acc[jj]);
    // ---- ticket: last block computes FC2 + sigmoid ----
    __threadfence();
    if (t == 0) last = (atomicAdd(ticket, 1) == NFC1B - 1);
    __syncthreads();
    if (last && t < NGRAPH) {
        float a = bf2[0];
        for (int j = 0; j < 64; ++j) {
            float v = unsafeAtomicAdd(&out1[t * 64 + j], 0.f);  // coherent read
            a += fmaxf(v + bf1[j], 0.f) * wf2[j];
        }
        out[t] = 1.f / (1.f + expf(-a));
    }
}

extern "C" void kernel_launch(void* const* d_in, const int* in_sizes, int n_in,
                              void* d_out, int out_size, void* d_ws, size_t ws_size,
                              hipStream_t stream) {
    const float* x   = (const float*)d_in[0];
    const int*   ei  = (const int*)d_in[1];
    const float* ew  = (const float*)d_in[2];
    const float* W1  = (const float*)d_in[3];
    const float* b1  = (const float*)d_in[4];
    const float* W2  = (const float*)d_in[5];
    const float* b2  = (const float*)d_in[6];
    const float* Wf1 = (const float*)d_in[7];
    const float* bf1 = (const float*)d_in[8];
    const float* Wf2 = (const float*)d_in[9];
    const float* bf2 = (const float*)d_in[10];
    float* out = (float*)d_out;

    char* ws = (char*)d_ws;
    size_t off = 0;
    auto alloc = [&](size_t bytes) {
        void* p = ws + off;
        off += (bytes + 255) & ~(size_t)255;
        return p;
    };
    uint2* es2 = (uint2*)alloc((size_t)N_NODES * CAP * 8);     // 57.3 MB
    // union region: es1 (34.8 MB, dies after k_sub) overlaps xl1/xl2/h2 (16.4 MB)
    char*  uni = (char*)alloc((size_t)NBIN * BINCAP * 8);
    uint2* es1 = (uint2*)uni;
    float* xl1 = (float*)uni;                                   // born at k_gemm1
    float* xl2 = xl1 + (size_t)N_NODES * F1;
    float* h2  = xl2 + (size_t)N_NODES * F2;
    float* deg_part = (float*)alloc((size_t)NBIN * SEG * 256 * 4);  // 2.0 MB
    float* dinv = (float*)alloc((size_t)N_NODES * 4);
    int*   cnta = (int*)alloc((size_t)N_NODES * 4);
    int*   gcur = (int*)alloc((size_t)NBIN * 4);
    float* out1 = (float*)alloc(64 * 64 * 4);
    int*   ticket = (int*)alloc(256);

    k_zero<<<17, 256, 0, stream>>>(gcur, out1, ticket);
    k_bin<<<(N_EDGES + EPB - 1) / EPB, 512, 0, stream>>>(ei, ew, gcur, es1);
    k_degp<<<NBIN * SEG, 256, 0, stream>>>(gcur, es1, deg_part);
    k_dinv<<<NBIN, 256, 0, stream>>>(deg_part, dinv);
    k_sub<<<NBIN, 1024, 0, stream>>>(gcur, es1, dinv, es2, cnta);
    k_gemm1<<<N_NODES / 128, 256, 0, stream>>>(x, W1, xl1);
    k_gather1<<<N_NODES / 32, 256, 0, stream>>>(cnta, es2, xl1, dinv, b1, W2, xl2);
    k_gather2<<<N_NODES / 64, 256, 0, stream>>>(cnta, es2, xl2, dinv, b2, h2);
    k_fc1<<<NFC1B, 256, 0, stream>>>(h2, Wf1, out1, ticket, bf1, Wf2, bf2, out);
}

// Round 13
// 343.411 us; speedup vs baseline: 1.3239x; 1.0310x over previous
//
#include <hip/hip_runtime.h>
#include <math.h>

#define N_NODES 64000
#define N_EDGES 3200000
#define F0 1000
#define F1 32
#define F2 16
#define NGRAPH 64
#define KC 128            // 16000 = 125 blocks x 128
#define NBIN 250          // 256 nodes per bin
#define BINCAP 17408      // level-1 slots per bin (mean ~15.9K incl. padding)
#define EPB 4096          // edges per binning block
#define SLOTS 38          // LDS staging slots per bin
#define CAP 112           // per-node bucket capacity (deg ~ Poisson(50))
#define SEG 8             // segments for k_degp

// ---------------- zero scratch counters ----------------
__global__ __launch_bounds__(256) void k_zero(int* __restrict__ gcur,
                                              float* __restrict__ out1) {
    int t = blockIdx.x * 256 + threadIdx.x;
    if (t < NBIN) gcur[t] = 0;
    if (t < NGRAPH * 64) out1[t] = 0.f;
}

// ---------------- level 1: group edges by col>>8 ----------------
// es1 entry: word0 = row | (col&255)<<17 ; word1 = fp32 weight. Pads are (0,0) -> w==0.
// 512 threads (16 waves/CU at 2 blocks/CU) hide LDS-atomic latency.
// Flush: parallel atomics (1 thread/bin) -> barrier -> wave burst writes.
__global__ __launch_bounds__(512) void k_bin(const int* __restrict__ ei,
                                             const float* __restrict__ ew,
                                             int* __restrict__ gcur,
                                             uint2* __restrict__ es1) {
    __shared__ uint2 stage[NBIN * SLOTS];   // 76 KB
    __shared__ int scnt[256];
    __shared__ int gbase[256];
    int t = threadIdx.x;
    if (t < 256) scnt[t] = 0;
    __syncthreads();
    int e0 = blockIdx.x * EPB;
#pragma unroll
    for (int r = 0; r < EPB / 512; ++r) {
        int e = e0 + r * 512 + t;
        if (e < N_EDGES) {
            int row = ei[e], c = ei[N_EDGES + e];
            float w = ew[e];
            int b = c >> 8;
            unsigned w0 = (unsigned)row | ((unsigned)(c & 255) << 17);
            int pos = atomicAdd(&scnt[b], 1);
            if (pos < SLOTS) {
                stage[b * SLOTS + pos] = make_uint2(w0, __float_as_uint(w));
            } else {  // rare overflow: aligned run of 8, 1 real + 7 pads
                int gb = atomicAdd(&gcur[b], 8);
                uint2* dst = &es1[(size_t)b * BINCAP + gb];
                dst[0] = make_uint2(w0, __float_as_uint(w));
#pragma unroll
                for (int z = 1; z < 8; ++z) dst[z] = make_uint2(0u, 0u);
            }
        }
    }
    __syncthreads();
    // phase 1: all bin reservations in parallel (latency overlaps)
    if (t < NBIN) {
        int cn = scnt[t]; if (cn > SLOTS) cn = SLOTS;
        int rn = (cn + 7) & ~7;              // line-aligned run
        gbase[t] = atomicAdd(&gcur[t], rn);
    }
    __syncthreads();                          // gbase visible to all
    // phase 2: wave-cooperative coalesced burst writes (8 waves)
    int wv = t >> 6, lane = t & 63;
    for (int b = wv; b < NBIN; b += 8) {
        int cn = scnt[b]; if (cn > SLOTS) cn = SLOTS;
        int rn = (cn + 7) & ~7;
        int gb = gbase[b];
        if (lane < rn) {
            uint2 v = (lane < cn) ? stage[b * SLOTS + lane] : make_uint2(0u, 0u);
            es1[(size_t)b * BINCAP + gb + lane] = v;
        }
    }
}

// ---------------- weighted degree, segmented partials (no global atomics) ----------------
__global__ __launch_bounds__(256) void k_degp(const int* __restrict__ gcur,
                                              const uint2* __restrict__ es1,
                                              float* __restrict__ deg_part) {
    __shared__ float dacc[256];
    int t = threadIdx.x;
    int bin = blockIdx.x >> 3, seg = blockIdx.x & (SEG - 1);
    dacc[t] = 0.f;
    __syncthreads();
    int cnt1 = gcur[bin];
    int chunk = (cnt1 + SEG - 1) / SEG;
    int lo = seg * chunk, hi = lo + chunk; if (hi > cnt1) hi = cnt1;
    const uint2* bp = &es1[(size_t)bin * BINCAP];
    for (int i = lo + t; i < hi; i += 256) {
        uint2 ed = bp[i];
        atomicAdd(&dacc[ed.x >> 17], __uint_as_float(ed.y));  // pads add 0
    }
    __syncthreads();
    deg_part[(size_t)blockIdx.x * 256 + t] = dacc[t];
}

__global__ __launch_bounds__(256) void k_dinv(const float* __restrict__ deg_part,
                                              float* __restrict__ dinv) {
    int n = blockIdx.x * 256 + threadIdx.x;   // bin = blockIdx.x
    float s = 0.f;
#pragma unroll
    for (int seg = 0; seg < SEG; ++seg)
        s += deg_part[((size_t)blockIdx.x * SEG + seg) * 256 + threadIdx.x];
    dinv[n] = rsqrtf(s + 1.0f);               // +1 = self-loop
}

// ---------------- level 2: scatter into per-node buckets with PRE-NORMALIZED weight ----------------
__global__ __launch_bounds__(1024) void k_sub(const int* __restrict__ gcur,
                                              const uint2* __restrict__ es1,
                                              const float* __restrict__ dinv,
                                              uint2* __restrict__ es2,
                                              int* __restrict__ cnta) {
    __shared__ int slot[256];
    __shared__ float dinvc[256];
    int t = threadIdx.x, bin = blockIdx.x;
    if (t < 256) { slot[t] = 0; dinvc[t] = dinv[bin * 256 + t]; }
    __syncthreads();
    int cnt1 = gcur[bin];
    const uint2* bp = &es1[(size_t)bin * BINCAP];
    for (int i = t; i < cnt1; i += 1024) {
        uint2 ed = bp[i];
        if (ed.y != 0u) {   // skip pads
            int c8 = ed.x >> 17;
            int row = ed.x & 0x1FFFF;
            float nv = dinv[row] * __uint_as_float(ed.y) * dinvc[c8];
            int p = atomicAdd(&slot[c8], 1);
            if (p < CAP)
                es2[((size_t)(bin * 256 + c8)) * CAP + p] =
                    make_uint2((unsigned)row, __float_as_uint(nv));
        }
    }
    __syncthreads();
    if (t < 256) {
        int c = slot[t]; if (c > CAP) c = CAP;
        cnta[bin * 256 + t] = c;
    }
}

// ---------------- GEMM1: xl1[N,32] = x[N,1000] @ W1[1000,32], double-buffered ----------------
__global__ __launch_bounds__(256) void k_gemm1(const float* __restrict__ x,
                                               const float* __restrict__ W,
                                               float* __restrict__ xl) {
    __shared__ float xs[2][32][132];
    __shared__ float ws[2][32][32];
    int t = threadIdx.x;
    int row0 = blockIdx.x * 128;
    int rsub = t >> 3;
    int kk4  = (t & 7) * 4;
    int tr = t >> 3;
    int tc = t & 7;

    float acc[4][4];
#pragma unroll
    for (int i = 0; i < 4; ++i)
#pragma unroll
        for (int j = 0; j < 4; ++j) acc[i][j] = 0.f;

    auto stage = [&](int k0, int buf) {
        int idx = t * 4;
        int gidx = k0 * F1 + idx;
        float4 v = make_float4(0.f, 0.f, 0.f, 0.f);
        if (gidx + 3 < F0 * F1) v = *(const float4*)&W[gidx];
        *(float4*)&((float*)ws[buf])[idx] = v;
#pragma unroll
        for (int p = 0; p < 4; ++p) {
            int r = p * 32 + rsub;
            float4 xv = make_float4(0.f, 0.f, 0.f, 0.f);
            if (k0 + kk4 < F0)
                xv = *(const float4*)&x[(size_t)(row0 + r) * F0 + k0 + kk4];
            xs[buf][kk4 + 0][r] = xv.x; xs[buf][kk4 + 1][r] = xv.y;
            xs[buf][kk4 + 2][r] = xv.z; xs[buf][kk4 + 3][r] = xv.w;
        }
    };
    auto compute = [&](int buf) {
#pragma unroll 8
        for (int kk = 0; kk < 32; ++kk) {
            float4 xa = *(const float4*)&xs[buf][kk][tr * 4];
            float4 wv = *(const float4*)&ws[buf][kk][tc * 4];
            float xv[4] = {xa.x, xa.y, xa.z, xa.w};
            float wl[4] = {wv.x, wv.y, wv.z, wv.w};
#pragma unroll
            for (int i = 0; i < 4; ++i)
#pragma unroll
                for (int j = 0; j < 4; ++j) acc[i][j] += xv[i] * wl[j];
        }
    };

    stage(0, 0);
    int buf = 0;
    for (int c = 0; c < 31; ++c) {
        __syncthreads();
        stage((c + 1) * 32, buf ^ 1);   // loads for c+1 fly under compute of c
        compute(buf);
        buf ^= 1;
    }
    __syncthreads();
    compute(buf);

#pragma unroll
    for (int i = 0; i < 4; ++i) {
        int row = row0 + tr * 4 + i;
        float4 v = make_float4(acc[i][0], acc[i][1], acc[i][2], acc[i][3]);
        *(float4*)&xl[(size_t)row * F1 + tc * 4] = v;
    }
}

// ---------------- gather layer1 + finish + GEMM2 fused ----------------
__global__ __launch_bounds__(256) void k_gather1(const int* __restrict__ cnta,
                                                 const uint2* __restrict__ es2,
                                                 const float* __restrict__ xl1,
                                                 const float* __restrict__ dinv,
                                                 const float* __restrict__ b1,
                                                 const float* __restrict__ W2,
                                                 float* __restrict__ xl2) {
    __shared__ float h1s[32][33];
    __shared__ float w2s[512];
    int t = threadIdx.x;
    if (t < 128) *(float4*)&w2s[t * 4] = *(const float4*)&W2[t * 4];
    int n = blockIdx.x * 32 + (t >> 3);
    int f4 = (t & 7) * 4;
    int cnt = cnta[n];
    float din = dinv[n];
    const uint2* bp = &es2[(size_t)n * CAP];
    float ax = 0.f, ay = 0.f, az = 0.f, aw = 0.f;
    float bx = 0.f, by = 0.f, bz = 0.f, bw = 0.f;
    int i = 0;
    uint4 cur = make_uint4(0u, 0u, 0u, 0u);
    if (cnt >= 2) cur = *(const uint4*)&bp[0];
    for (; i + 1 < cnt; i += 2) {
        uint4 nxt = make_uint4(0u, 0u, 0u, 0u);
        if (i + 3 < cnt) nxt = *(const uint4*)&bp[i + 2];
        float4 x0 = *(const float4*)&xl1[(size_t)cur.x * F1 + f4];
        float4 x1 = *(const float4*)&xl1[(size_t)cur.z * F1 + f4];
        float n0 = __uint_as_float(cur.y), n1 = __uint_as_float(cur.w);
        ax += n0 * x0.x; ay += n0 * x0.y; az += n0 * x0.z; aw += n0 * x0.w;
        bx += n1 * x1.x; by += n1 * x1.y; bz += n1 * x1.z; bw += n1 * x1.w;
        cur = nxt;
    }
    if (i < cnt) {
        uint2 ed = bp[i];
        float4 x0 = *(const float4*)&xl1[(size_t)ed.x * F1 + f4];
        float n0 = __uint_as_float(ed.y);
        ax += n0 * x0.x; ay += n0 * x0.y; az += n0 * x0.z; aw += n0 * x0.w;
    }
    float d2 = din * din;
    float4 sv = *(const float4*)&xl1[(size_t)n * F1 + f4];
    int nn = t >> 3;
    h1s[nn][f4 + 0] = fmaxf(ax + bx + d2 * sv.x + b1[f4 + 0], 0.f);
    h1s[nn][f4 + 1] = fmaxf(ay + by + d2 * sv.y + b1[f4 + 1], 0.f);
    h1s[nn][f4 + 2] = fmaxf(az + bz + d2 * sv.z + b1[f4 + 2], 0.f);
    h1s[nn][f4 + 3] = fmaxf(aw + bw + d2 * sv.w + b1[f4 + 3], 0.f);
    __syncthreads();
    int j0 = (t & 7) * 2;
    float a0 = 0.f, a1 = 0.f;
#pragma unroll 8
    for (int k = 0; k < 32; ++k) {
        float hv = h1s[nn][k];
        a0 += hv * w2s[k * 16 + j0];
        a1 += hv * w2s[k * 16 + j0 + 1];
    }
    *(float2*)&xl2[(size_t)(blockIdx.x * 32 + nn) * F2 + j0] = make_float2(a0, a1);
}

// ---------------- gather layer2 + finish -> h2 ----------------
__global__ __launch_bounds__(256) void k_gather2(const int* __restrict__ cnta,
                                                 const uint2* __restrict__ es2,
                                                 const float* __restrict__ xl2,
                                                 const float* __restrict__ dinv,
                                                 const float* __restrict__ b2,
                                                 float* __restrict__ h2) {
    int t = threadIdx.x;
    int n = blockIdx.x * 64 + (t >> 2);
    int f4 = (t & 3) * 4;
    int cnt = cnta[n];
    float din = dinv[n];
    const uint2* bp = &es2[(size_t)n * CAP];
    float ax = 0.f, ay = 0.f, az = 0.f, aw = 0.f;
    float bx = 0.f, by = 0.f, bz = 0.f, bw = 0.f;
    int i = 0;
    uint4 cur = make_uint4(0u, 0u, 0u, 0u);
    if (cnt >= 2) cur = *(const uint4*)&bp[0];
    for (; i + 1 < cnt; i += 2) {
        uint4 nxt = make_uint4(0u, 0u, 0u, 0u);
        if (i + 3 < cnt) nxt = *(const uint4*)&bp[i + 2];
        float4 x0 = *(const float4*)&xl2[(size_t)cur.x * F2 + f4];
        float4 x1 = *(const float4*)&xl2[(size_t)cur.z * F2 + f4];
        float n0 = __uint_as_float(cur.y), n1 = __uint_as_float(cur.w);
        ax += n0 * x0.x; ay += n0 * x0.y; az += n0 * x0.z; aw += n0 * x0.w;
        bx += n1 * x1.x; by += n1 * x1.y; bz += n1 * x1.z; bw += n1 * x1.w;
        cur = nxt;
    }
    if (i < cnt) {
        uint2 ed = bp[i];
        float4 x0 = *(const float4*)&xl2[(size_t)ed.x * F2 + f4];
        float n0 = __uint_as_float(ed.y);
        ax += n0 * x0.x; ay += n0 * x0.y; az += n0 * x0.z; aw += n0 * x0.w;
    }
    float d2 = din * din;
    float4 sv = *(const float4*)&xl2[(size_t)n * F2 + f4];
    float4 o;
    o.x = fmaxf(ax + bx + d2 * sv.x + b2[f4 + 0], 0.f);
    o.y = fmaxf(ay + by + d2 * sv.y + b2[f4 + 1], 0.f);
    o.z = fmaxf(az + bz + d2 * sv.z + b2[f4 + 2], 0.f);
    o.w = fmaxf(aw + bw + d2 * sv.w + b2[f4 + 3], 0.f);
    *(float4*)&h2[(size_t)n * F2 + f4] = o;
}

// ---------------- FC1 partial: KC=128 (16000 = 125 x 128), padded LDS ----------------
__global__ __launch_bounds__(256) void k_fc1(const float* __restrict__ h2,
                                             const float* __restrict__ wf1,
                                             float* __restrict__ out1) {
    __shared__ float wfs[KC * 64];     // 32 KB
    __shared__ float h2s[64][KC + 1];  // 33 KB, stride 129 kills bank conflicts
    int t = threadIdx.x;
    int k0 = blockIdx.x * KC;
    for (int idx = t * 4; idx < KC * 64; idx += 1024)
        *(float4*)&wfs[idx] = *(const float4*)&wf1[(size_t)k0 * 64 + idx];
    for (int idx = t; idx < 64 * (KC / 4); idx += 256) {
        int g = idx >> 5, j = idx & 31;   // KC/4 = 32 float4 per row
        *(float4*)&h2s[g][j * 4] = *(const float4*)&h2[(size_t)g * 16000 + k0 + j * 4];
    }
    __syncthreads();
    int g = t >> 2, jg = t & 3;
    float acc[16];
#pragma unroll
    for (int jj = 0; jj < 16; ++jj) acc[jj] = 0.f;
#pragma unroll 4
    for (int k = 0; k < KC; ++k) {
        float hv = h2s[g][k];
#pragma unroll
        for (int j4 = 0; j4 < 4; ++j4) {
            float4 wv = *(const float4*)&wfs[k * 64 + jg * 16 + j4 * 4];
            acc[j4 * 4 + 0] += hv * wv.x; acc[j4 * 4 + 1] += hv * wv.y;
            acc[j4 * 4 + 2] += hv * wv.z; acc[j4 * 4 + 3] += hv * wv.w;
        }
    }
#pragma unroll
    for (int jj = 0; jj < 16; ++jj)
        unsafeAtomicAdd(&out1[g * 64 + jg * 16 + jj], acc[jj]);
}

// ---------------- FC2 + sigmoid ----------------
__global__ void k_fc2(const float* __restrict__ out1, const float* __restrict__ bf1,
                      const float* __restrict__ wf2, const float* __restrict__ bf2,
                      float* __restrict__ out) {
    int g = threadIdx.x;
    if (g < NGRAPH) {
        float acc = bf2[0];
        for (int j = 0; j < 64; ++j)
            acc += fmaxf(out1[g * 64 + j] + bf1[j], 0.f) * wf2[j];
        out[g] = 1.f / (1.f + expf(-acc));
    }
}

extern "C" void kernel_launch(void* const* d_in, const int* in_sizes, int n_in,
                              void* d_out, int out_size, void* d_ws, size_t ws_size,
                              hipStream_t stream) {
    const float* x   = (const float*)d_in[0];
    const int*   ei  = (const int*)d_in[1];
    const float* ew  = (const float*)d_in[2];
    const float* W1  = (const float*)d_in[3];
    const float* b1  = (const float*)d_in[4];
    const float* W2  = (const float*)d_in[5];
    const float* b2  = (const float*)d_in[6];
    const float* Wf1 = (const float*)d_in[7];
    const float* bf1 = (const float*)d_in[8];
    const float* Wf2 = (const float*)d_in[9];
    const float* bf2 = (const float*)d_in[10];
    float* out = (float*)d_out;

    char* ws = (char*)d_ws;
    size_t off = 0;
    auto alloc = [&](size_t bytes) {
        void* p = ws + off;
        off += (bytes + 255) & ~(size_t)255;
        return p;
    };
    uint2* es2 = (uint2*)alloc((size_t)N_NODES * CAP * 8);     // 57.3 MB
    // union region: es1 (34.8 MB, dies after k_sub) overlaps xl1/xl2/h2 (16.4 MB)
    char*  uni = (char*)alloc((size_t)NBIN * BINCAP * 8);
    uint2* es1 = (uint2*)uni;
    float* xl1 = (float*)uni;                                   // born at k_gemm1
    float* xl2 = xl1 + (size_t)N_NODES * F1;
    float* h2  = xl2 + (size_t)N_NODES * F2;
    float* deg_part = (float*)alloc((size_t)NBIN * SEG * 256 * 4);  // 2.0 MB
    float* dinv = (float*)alloc((size_t)N_NODES * 4);
    int*   cnta = (int*)alloc((size_t)N_NODES * 4);
    int*   gcur = (int*)alloc((size_t)NBIN * 4);
    float* out1 = (float*)alloc(64 * 64 * 4);

    k_zero<<<17, 256, 0, stream>>>(gcur, out1);
    k_bin<<<(N_EDGES + EPB - 1) / EPB, 512, 0, stream>>>(ei, ew, gcur, es1);
    k_degp<<<NBIN * SEG, 256, 0, stream>>>(gcur, es1, deg_part);
    k_dinv<<<NBIN, 256, 0, stream>>>(deg_part, dinv);
    k_sub<<<NBIN, 1024, 0, stream>>>(gcur, es1, dinv, es2, cnta);
    k_gemm1<<<N_NODES / 128, 256, 0, stream>>>(x, W1, xl1);
    k_gather1<<<N_NODES / 32, 256, 0, stream>>>(cnta, es2, xl1, dinv, b1, W2, xl2);
    k_gather2<<<N_NODES / 64, 256, 0, stream>>>(cnta, es2, xl2, dinv, b2, h2);
    k_fc1<<<16000 / KC, 256, 0, stream>>>(h2, Wf1, out1);
    k_fc2<<<1, 64, 0, stream>>>(out1, bf1, Wf2, bf2, out);
}